// Round 10
// baseline (70.226 us; speedup 1.0000x reference)
//
#include <hip/hip_runtime.h>
#include <hip/hip_bf16.h>
#include <math.h>

#define NTOK 10000
#define BATCH 2
#define CDIM 128
#define NHEAD 4
#define NPNT 20
#define DHEAD 32
#define HWDIM 100
#define MROWS (BATCH * NTOK)
#define OCAT 368   // 128 value + 160 off + 80 attn
#define PTOK 8     // 8x8 tokens per patch
#define PHALO 4    // halo cells each side
#define PDIM 16    // PTOK + 2*PHALO
#define NPATCH 13  // ceil(100/8)
#define CELLPAD 40 // bf16 per cell in LDS (stride 80B: 16B-aligned)

typedef __attribute__((ext_vector_type(8))) short short8v;
typedef __attribute__((ext_vector_type(4))) short short4v;
typedef __attribute__((ext_vector_type(4))) float f32x4;

__device__ __forceinline__ float asf(unsigned u) {
  union { unsigned u; float f; } c; c.u = u; return c.f;
}

// unpack 8 bf16 (16B) and accumulate w * g into two f32x4 accumulators
__device__ __forceinline__ void acc_cell(const __hip_bfloat16* p, float w,
                                         f32x4& a0, f32x4& a1) {
  int4 u = *(const int4*)p;
  f32x4 g0, g1;
  g0.x = asf(((unsigned)u.x) << 16); g0.y = asf(((unsigned)u.x) & 0xFFFF0000u);
  g0.z = asf(((unsigned)u.y) << 16); g0.w = asf(((unsigned)u.y) & 0xFFFF0000u);
  g1.x = asf(((unsigned)u.z) << 16); g1.y = asf(((unsigned)u.z) & 0xFFFF0000u);
  g1.z = asf(((unsigned)u.w) << 16); g1.w = asf(((unsigned)u.w) & 0xFFFF0000u);
  a0 += g0 * w;
  a1 += g1 * w;
}

__device__ __forceinline__ void cvt8_store(__hip_bfloat16* dst, float4 v0,
                                           float4 v1) {
  dst[0] = __float2bfloat16(v0.x); dst[1] = __float2bfloat16(v0.y);
  dst[2] = __float2bfloat16(v0.z); dst[3] = __float2bfloat16(v0.w);
  dst[4] = __float2bfloat16(v1.x); dst[5] = __float2bfloat16(v1.y);
  dst[6] = __float2bfloat16(v1.z); dst[7] = __float2bfloat16(v1.w);
}

// ---------------------------------------------------------------------------
// proj1: 512 thr, grid(313). Block = 64 rows x 368 outs (3 tiles of 128).
// A = (query+query_pos) fp32 -> bf16 staged + fragments hoisted ONCE.
// W tiles read fp32 from the three weight mats, converted inline (L2-hot).
// Bias applied inline in the epilogue; scatter to head-major buffers.
// 8 waves = 2 (rows) x 4 (cols); wave = 32x32 via 2x2 frags x 4 K-steps.
// ---------------------------------------------------------------------------
__global__ __launch_bounds__(512) void proj1_kernel(
    const float* __restrict__ query, const float* __restrict__ qpos,
    const float* __restrict__ W_val, const float* __restrict__ b_val,
    const float* __restrict__ W_off, const float* __restrict__ b_off,
    const float* __restrict__ W_attn, const float* __restrict__ b_attn,
    __hip_bfloat16* __restrict__ value, __hip_bfloat16* __restrict__ offo,
    float* __restrict__ attno) {
  __shared__ __hip_bfloat16 qa[64][128];   // 16 KB
  __shared__ __hip_bfloat16 wb[128][128];  // 32 KB
  const int t = threadIdx.x;
  const int r0 = blockIdx.x * 64;

  // stage A: 1024 granules over 512 threads (2 iters)
#pragma unroll
  for (int i = 0; i < 2; ++i) {
    int lin = t + 512 * i;  // 0..1023
    int r = lin >> 4, g = lin & 15;
    int c = g << 3;
    float4 v0 = make_float4(0.f, 0.f, 0.f, 0.f);
    float4 v1 = make_float4(0.f, 0.f, 0.f, 0.f);
    if (r0 + r < MROWS) {
      const float* p = query + (size_t)(r0 + r) * CDIM + c;
      v0 = *(const float4*)p;
      v1 = *(const float4*)(p + 4);
      const float* p2 = qpos + (size_t)(r0 + r) * CDIM + c;
      float4 u0 = *(const float4*)p2;
      float4 u1 = *(const float4*)(p2 + 4);
      v0.x += u0.x; v0.y += u0.y; v0.z += u0.z; v0.w += u0.w;
      v1.x += u1.x; v1.y += u1.y; v1.z += u1.z; v1.w += u1.w;
    }
    cvt8_store(&qa[r][(g ^ (r & 7)) << 3], v0, v1);
  }
  __syncthreads();

  const int wid = t >> 6;         // 0..7
  const int lane = t & 63;
  const int wr = (wid >> 2) * 32; // 0 or 32
  const int wc = (wid & 3) * 32;  // 0,32,64,96
  const int lrow = lane & 15;
  const int lk = lane >> 4;

  // hoist A fragments (reused across all 3 W tiles)
  short8v afr[4][2];
  {
    int ra0 = wr + lrow, ra1 = wr + 16 + lrow;
#pragma unroll
    for (int kk = 0; kk < 4; ++kk) {
      int gb = kk * 4 + lk;
      afr[kk][0] = *(const short8v*)&qa[ra0][(gb ^ (ra0 & 7)) << 3];
      afr[kk][1] = *(const short8v*)&qa[ra1][(gb ^ (ra1 & 7)) << 3];
    }
  }

  for (int ti = 0; ti < 3; ++ti) {
    const int ot = ti * 128;
    __syncthreads();  // previous tile's wb readers done
    // stage W tile: 2048 granules over 512 threads, fp32 -> bf16 inline
#pragma unroll
    for (int i = 0; i < 4; ++i) {
      int lin = t + 512 * i;
      int r = lin >> 4;   // 0..127
      int g = lin & 15;
      int grow = ot + r;
      float4 w0 = make_float4(0.f, 0.f, 0.f, 0.f);
      float4 w1 = make_float4(0.f, 0.f, 0.f, 0.f);
      if (grow < OCAT) {
        const float* src;
        if (grow < 128) src = W_val + (size_t)grow * 128;
        else if (grow < 288) src = W_off + (size_t)(grow - 128) * 128;
        else src = W_attn + (size_t)(grow - 288) * 128;
        w0 = *(const float4*)(src + (g << 3));
        w1 = *(const float4*)(src + (g << 3) + 4);
      }
      cvt8_store(&wb[r][(g ^ (r & 7)) << 3], w0, w1);
    }
    __syncthreads();

    f32x4 acc[2][2];
#pragma unroll
    for (int mi = 0; mi < 2; ++mi)
#pragma unroll
      for (int ni = 0; ni < 2; ++ni) acc[mi][ni] = (f32x4)(0.f);

#pragma unroll
    for (int kk = 0; kk < 4; ++kk) {
      const int gb = kk * 4 + lk;
      int rb0 = wc + lrow, rb1 = wc + 16 + lrow;
      short8v b0 = *(const short8v*)&wb[rb0][(gb ^ (rb0 & 7)) << 3];
      short8v b1 = *(const short8v*)&wb[rb1][(gb ^ (rb1 & 7)) << 3];
      acc[0][0] = __builtin_amdgcn_mfma_f32_16x16x32_bf16(afr[kk][0], b0, acc[0][0], 0, 0, 0);
      acc[0][1] = __builtin_amdgcn_mfma_f32_16x16x32_bf16(afr[kk][0], b1, acc[0][1], 0, 0, 0);
      acc[1][0] = __builtin_amdgcn_mfma_f32_16x16x32_bf16(afr[kk][1], b0, acc[1][0], 0, 0, 0);
      acc[1][1] = __builtin_amdgcn_mfma_f32_16x16x32_bf16(afr[kk][1], b1, acc[1][1], 0, 0, 0);
    }

    // C/D: col = lane&15, row = (lane>>4)*4 + reg
#pragma unroll
    for (int mi = 0; mi < 2; ++mi) {
#pragma unroll
      for (int ni = 0; ni < 2; ++ni) {
#pragma unroll
        for (int reg = 0; reg < 4; ++reg) {
          int r = r0 + wr + mi * 16 + (lane >> 4) * 4 + reg;
          int o = ot + wc + ni * 16 + (lane & 15);
          if (r >= MROWS || o >= OCAT) continue;
          float bv;
          if (o < 128) bv = b_val[o];
          else if (o < 288) bv = b_off[o - 128];
          else bv = b_attn[o - 288];
          float v = acc[mi][ni][reg] + bv;
          int b = r >= NTOK ? 1 : 0;
          int n = r - b * NTOK;
          if (o < 128) {
            int h = o >> 5, rem = o & 31;
            value[(((size_t)b * NHEAD + h) * NTOK + n) * 32 + rem] =
                __float2bfloat16(v);
          } else if (o < 288) {
            int oo = o - 128, h = oo / 40, rem = oo - h * 40;
            offo[(((size_t)b * NHEAD + h) * NTOK + n) * 40 + rem] =
                __float2bfloat16(v);
          } else {
            int oo = o - 288, h = oo / 20, rem = oo - h * 20;
            attno[(((size_t)b * NHEAD + h) * NTOK + n) * 20 + rem] = v;
          }
        }
      }
    }
  }
}

// ---------------------------------------------------------------------------
// proj2: 512 thr, grid(313). out = (A@W1^T + b1)@W2^T + b2 + resid, A = outat
// bf16. Two sequential MFMA stages; t1 stored bf16 back into the A buffer
// (fragments already hoisted), W1/W2 read fp32 + converted inline (no fold
// precompute kernel needed).
// ---------------------------------------------------------------------------
__global__ __launch_bounds__(512) void proj2_kernel(
    const __hip_bfloat16* __restrict__ outat, const float* __restrict__ W1,
    const float* __restrict__ b1, const float* __restrict__ W2,
    const float* __restrict__ b2, const float* __restrict__ resid,
    float* __restrict__ out) {
  __shared__ __hip_bfloat16 qa[64][128];
  __shared__ __hip_bfloat16 wb[128][128];
  const int t = threadIdx.x;
  const int r0 = blockIdx.x * 64;

#pragma unroll
  for (int i = 0; i < 2; ++i) {
    int lin = t + 512 * i;
    int r = lin >> 4, g = lin & 15;
    short8v v = (short8v)(short)0;
    if (r0 + r < MROWS)
      v = *(const short8v*)(outat + (size_t)(r0 + r) * CDIM + (g << 3));
    *(short8v*)&qa[r][(g ^ (r & 7)) << 3] = v;
  }
  __syncthreads();

  const int wid = t >> 6;
  const int lane = t & 63;
  const int wr = (wid >> 2) * 32;
  const int wc = (wid & 3) * 32;
  const int lrow = lane & 15;
  const int lk = lane >> 4;

  short8v afr[4][2];
  {
    int ra0 = wr + lrow, ra1 = wr + 16 + lrow;
#pragma unroll
    for (int kk = 0; kk < 4; ++kk) {
      int gb = kk * 4 + lk;
      afr[kk][0] = *(const short8v*)&qa[ra0][(gb ^ (ra0 & 7)) << 3];
      afr[kk][1] = *(const short8v*)&qa[ra1][(gb ^ (ra1 & 7)) << 3];
    }
  }

  // ---- stage 1: t1 = A@W1^T + b1 -> qa (bf16) ----
#pragma unroll
  for (int i = 0; i < 4; ++i) {
    int lin = t + 512 * i;
    int r = lin >> 4, g = lin & 15;
    const float* src = W1 + (size_t)r * 128;
    float4 w0 = *(const float4*)(src + (g << 3));
    float4 w1 = *(const float4*)(src + (g << 3) + 4);
    cvt8_store(&wb[r][(g ^ (r & 7)) << 3], w0, w1);
  }
  __syncthreads();

  f32x4 acc[2][2];
#pragma unroll
  for (int mi = 0; mi < 2; ++mi)
#pragma unroll
    for (int ni = 0; ni < 2; ++ni) acc[mi][ni] = (f32x4)(0.f);
#pragma unroll
  for (int kk = 0; kk < 4; ++kk) {
    const int gb = kk * 4 + lk;
    int rb0 = wc + lrow, rb1 = wc + 16 + lrow;
    short8v b0 = *(const short8v*)&wb[rb0][(gb ^ (rb0 & 7)) << 3];
    short8v b1v = *(const short8v*)&wb[rb1][(gb ^ (rb1 & 7)) << 3];
    acc[0][0] = __builtin_amdgcn_mfma_f32_16x16x32_bf16(afr[kk][0], b0, acc[0][0], 0, 0, 0);
    acc[0][1] = __builtin_amdgcn_mfma_f32_16x16x32_bf16(afr[kk][0], b1v, acc[0][1], 0, 0, 0);
    acc[1][0] = __builtin_amdgcn_mfma_f32_16x16x32_bf16(afr[kk][1], b0, acc[1][0], 0, 0, 0);
    acc[1][1] = __builtin_amdgcn_mfma_f32_16x16x32_bf16(afr[kk][1], b1v, acc[1][1], 0, 0, 0);
  }
  // write t1 into qa (all afr hoists completed before the last barrier)
#pragma unroll
  for (int mi = 0; mi < 2; ++mi) {
#pragma unroll
    for (int ni = 0; ni < 2; ++ni) {
#pragma unroll
      for (int reg = 0; reg < 4; ++reg) {
        int r = wr + mi * 16 + (lane >> 4) * 4 + reg;  // 0..63
        int o = wc + ni * 16 + (lane & 15);            // 0..127
        float v = acc[mi][ni][reg] + b1[o];
        qa[r][((o >> 3) ^ (r & 7)) * 8 + (o & 7)] = __float2bfloat16(v);
      }
    }
  }
  __syncthreads();

  // ---- stage 2: out = t1@W2^T + b2 + resid ----
  short8v afr2[4][2];
  {
    int ra0 = wr + lrow, ra1 = wr + 16 + lrow;
#pragma unroll
    for (int kk = 0; kk < 4; ++kk) {
      int gb = kk * 4 + lk;
      afr2[kk][0] = *(const short8v*)&qa[ra0][(gb ^ (ra0 & 7)) << 3];
      afr2[kk][1] = *(const short8v*)&qa[ra1][(gb ^ (ra1 & 7)) << 3];
    }
  }
#pragma unroll
  for (int i = 0; i < 4; ++i) {
    int lin = t + 512 * i;
    int r = lin >> 4, g = lin & 15;
    const float* src = W2 + (size_t)r * 128;
    float4 w0 = *(const float4*)(src + (g << 3));
    float4 w1 = *(const float4*)(src + (g << 3) + 4);
    cvt8_store(&wb[r][(g ^ (r & 7)) << 3], w0, w1);
  }
  __syncthreads();

#pragma unroll
  for (int mi = 0; mi < 2; ++mi)
#pragma unroll
    for (int ni = 0; ni < 2; ++ni) acc[mi][ni] = (f32x4)(0.f);
#pragma unroll
  for (int kk = 0; kk < 4; ++kk) {
    const int gb = kk * 4 + lk;
    int rb0 = wc + lrow, rb1 = wc + 16 + lrow;
    short8v b0 = *(const short8v*)&wb[rb0][(gb ^ (rb0 & 7)) << 3];
    short8v b1v = *(const short8v*)&wb[rb1][(gb ^ (rb1 & 7)) << 3];
    acc[0][0] = __builtin_amdgcn_mfma_f32_16x16x32_bf16(afr2[kk][0], b0, acc[0][0], 0, 0, 0);
    acc[0][1] = __builtin_amdgcn_mfma_f32_16x16x32_bf16(afr2[kk][0], b1v, acc[0][1], 0, 0, 0);
    acc[1][0] = __builtin_amdgcn_mfma_f32_16x16x32_bf16(afr2[kk][1], b0, acc[1][0], 0, 0, 0);
    acc[1][1] = __builtin_amdgcn_mfma_f32_16x16x32_bf16(afr2[kk][1], b1v, acc[1][1], 0, 0, 0);
  }
#pragma unroll
  for (int mi = 0; mi < 2; ++mi) {
#pragma unroll
    for (int ni = 0; ni < 2; ++ni) {
#pragma unroll
      for (int reg = 0; reg < 4; ++reg) {
        int r = r0 + wr + mi * 16 + (lane >> 4) * 4 + reg;
        int o = wc + ni * 16 + (lane & 15);
        if (r >= MROWS) continue;
        out[(size_t)r * CDIM + o] =
            acc[mi][ni][reg] + b2[o] + resid[(size_t)r * CDIM + o];
      }
    }
  }
}

// ---------------------------------------------------------------------------
// Sampling: 4 lanes/token, 8 dims/lane. bf16 patch in LDS (R8 structure).
// off/attn global loads HOISTED above the staging barrier (latency hidden
// under patch staging). Four corner accumulator pairs; deferred softmax norm.
// ---------------------------------------------------------------------------
__global__ __launch_bounds__(256) void sample_kernel(
    const __hip_bfloat16* __restrict__ value,
    const __hip_bfloat16* __restrict__ off, const float* __restrict__ attn,
    __hip_bfloat16* __restrict__ outat) {
  const int s = blockIdx.x & 7;
  const int pidx = blockIdx.x >> 3;
  const int PI = pidx % NPATCH, PJ = pidx / NPATCH;
  const int I0 = PI * PTOK, J0 = PJ * PTOK;
  const int b = s >> 2, h = s & 3;

  __shared__ __hip_bfloat16 patch[PDIM * PDIM][CELLPAD];
  const __hip_bfloat16* vglob = value + (size_t)s * NTOK * DHEAD;

  // hoisted per-token loads (issued before staging so latency hides)
  const int dl = threadIdx.x & 3;
  const int tok = threadIdx.x >> 2;
  const int li = tok & 7, lj = tok >> 3;
  const int i = I0 + li, j = J0 + lj;
  const bool tv = (i < HWDIM) && (j < HWDIM);
  const int n = tv ? (i * HWDIM + j) : 0;
  union { int4 v4[5]; unsigned u[20]; } of;
  union { float4 v4[5]; float f[20]; } at;
  {
    const int4* o4 = (const int4*)(off + ((size_t)s * NTOK + n) * 40);
    const float4* a4 = (const float4*)(attn + ((size_t)s * NTOK + n) * 20);
#pragma unroll
    for (int q = 0; q < 5; ++q) of.v4[q] = o4[q];
#pragma unroll
    for (int q = 0; q < 5; ++q) at.v4[q] = a4[q];
  }

  // stage patch: 256 cells x 64B, zeros outside image
#pragma unroll
  for (int it = 0; it < 4; ++it) {
    int lin = threadIdx.x + 256 * it;
    int cell = lin >> 2, part = lin & 3;
    int py = cell >> 4, px = cell & 15;
    int gy = J0 - PHALO + py;
    int gx = I0 - PHALO + px;
    short8v v = (short8v)(short)0;
    if (gy >= 0 && gy < HWDIM && gx >= 0 && gx < HWDIM)
      v = *(const short8v*)(vglob + ((size_t)(gy * HWDIM + gx)) * DHEAD +
                            part * 8);
    *(short8v*)&patch[cell][part * 8] = v;
  }
  __syncthreads();

  if (!tv) return;

  float ssum = 0.f;
#pragma unroll
  for (int p = 0; p < NPNT; ++p) {
    at.f[p] = __expf(at.f[p]);
    ssum += at.f[p];
  }
  const float inv = 1.f / ssum;

  const float fi = (float)i, fj = (float)j;
  f32x4 c0a = (f32x4)(0.f), c0b = (f32x4)(0.f);
  f32x4 c1a = (f32x4)(0.f), c1b = (f32x4)(0.f);
  f32x4 c2a = (f32x4)(0.f), c2b = (f32x4)(0.f);
  f32x4 c3a = (f32x4)(0.f), c3b = (f32x4)(0.f);
#pragma unroll
  for (int p = 0; p < NPNT; ++p) {
    const unsigned up = of.u[p];
    float x = fi + asf(up << 16);
    float y = fj + asf(up & 0xFFFF0000u);
    float aw = at.f[p];
    float x0f = floorf(x), y0f = floorf(y);
    int ix0 = (int)x0f, iy0 = (int)y0f;
    float wx1 = x - x0f, wy1 = y - y0f;
    float wx0 = 1.f - wx1, wy0 = 1.f - wy1;
    float wya = aw * wy0, wyb = aw * wy1;
    float w00 = wya * wx0, w01 = wya * wx1;
    float w10 = wyb * wx0, w11 = wyb * wx1;
    int ly = iy0 - (J0 - PHALO);
    int lx = ix0 - (I0 - PHALO);
    if ((unsigned)ly <= PDIM - 2 && (unsigned)lx <= PDIM - 2) {
      const __hip_bfloat16* pb = &patch[ly * PDIM + lx][dl * 8];
      acc_cell(pb, w00, c0a, c0b);
      acc_cell(pb + CELLPAD, w01, c1a, c1b);
      acc_cell(pb + PDIM * CELLPAD, w10, c2a, c2b);
      acc_cell(pb + PDIM * CELLPAD + CELLPAD, w11, c3a, c3b);
    } else {
      float wgt[4] = {w00, w01, w10, w11};
#pragma unroll
      for (int cy = 0; cy < 2; ++cy) {
        int iy = iy0 + cy;
        if (iy < 0 || iy >= HWDIM) continue;
#pragma unroll
        for (int cx = 0; cx < 2; ++cx) {
          int ix = ix0 + cx;
          if (ix < 0 || ix >= HWDIM) continue;
          acc_cell(vglob + ((size_t)(iy * HWDIM + ix)) * DHEAD + dl * 8,
                   wgt[cy * 2 + cx], c0a, c0b);
        }
      }
    }
  }
  f32x4 a0 = (c0a + c1a) + (c2a + c3a);
  f32x4 a1 = (c0b + c1b) + (c2b + c3b);

  union { short8v v8; __hip_bfloat16 hh[8]; } o;
#pragma unroll
  for (int k = 0; k < 4; ++k) {
    o.hh[k] = __float2bfloat16(a0[k] * inv);
    o.hh[4 + k] = __float2bfloat16(a1[k] * inv);
  }
  *(short8v*)(outat + ((size_t)b * NTOK + n) * CDIM + h * DHEAD + dl * 8) =
      o.v8;
}

extern "C" void kernel_launch(void* const* d_in, const int* in_sizes, int n_in,
                              void* d_out, int out_size, void* d_ws,
                              size_t ws_size, hipStream_t stream) {
  const float* query = (const float*)d_in[0];
  const float* query_pos = (const float*)d_in[1];
  const float* W_val = (const float*)d_in[2];
  const float* b_val = (const float*)d_in[3];
  const float* W_off = (const float*)d_in[4];
  const float* b_off = (const float*)d_in[5];
  const float* W_attn = (const float*)d_in[6];
  const float* b_attn = (const float*)d_in[7];
  const float* W_out1 = (const float*)d_in[8];
  const float* b_out1 = (const float*)d_in[9];
  const float* W_out2 = (const float*)d_in[10];
  const float* b_out2 = (const float*)d_in[11];
  float* out = (float*)d_out;

  char* ws = (char*)d_ws;
  __hip_bfloat16* value = (__hip_bfloat16*)ws;  // (B*NH,N,32) bf16
  ws += (size_t)MROWS * CDIM * 2;
  __hip_bfloat16* offb = (__hip_bfloat16*)ws;   // (B*NH,N,40) bf16
  ws += (size_t)MROWS * 160 * 2;
  float* attnb = (float*)ws;                    // (B*NH,N,20) f32
  ws += (size_t)MROWS * 80 * 4;
  __hip_bfloat16* outat = (__hip_bfloat16*)ws;  // (B,N,C) bf16

  proj1_kernel<<<313, 512, 0, stream>>>(query, query_pos, W_val, b_val, W_off,
                                        b_off, W_attn, b_attn, value, offb,
                                        attnb);

  sample_kernel<<<8 * NPATCH * NPATCH, 256, 0, stream>>>(value, offb, attnb,
                                                         outat);

  proj2_kernel<<<313, 512, 0, stream>>>(outat, W_out1, b_out1, W_out2, b_out2,
                                        query, out);
}

// Round 11
// 58.906 us; speedup vs baseline: 1.1922x; 1.1922x over previous
//
#include <hip/hip_runtime.h>
#include <hip/hip_bf16.h>
#include <math.h>

#define NTOK 10000
#define BATCH 2
#define CDIM 128
#define NHEAD 4
#define NPNT 20
#define DHEAD 32
#define HWDIM 100
#define MROWS (BATCH * NTOK)
#define OPAD 384   // 128 value rows + 4 heads x (40 off + 20 attn + 4 pad)
#define PTOK 8
#define PHALO 4
#define PDIM 16
#define NPATCH 13
#define CELLPAD 40 // bf16 per cell in LDS (stride 80B: 16B-aligned)

typedef __attribute__((ext_vector_type(8))) short short8v;
typedef __attribute__((ext_vector_type(4))) short short4v;
typedef __attribute__((ext_vector_type(4))) float f32x4;

__device__ __forceinline__ float asf(unsigned u) {
  union { unsigned u; float f; } c; c.u = u; return c.f;
}

// unpack 8 bf16 (16B) and accumulate w * g into two f32x4 accumulators
__device__ __forceinline__ void acc_cell(const __hip_bfloat16* p, float w,
                                         f32x4& a0, f32x4& a1) {
  int4 u = *(const int4*)p;
  f32x4 g0, g1;
  g0.x = asf(((unsigned)u.x) << 16); g0.y = asf(((unsigned)u.x) & 0xFFFF0000u);
  g0.z = asf(((unsigned)u.y) << 16); g0.w = asf(((unsigned)u.y) & 0xFFFF0000u);
  g1.x = asf(((unsigned)u.z) << 16); g1.y = asf(((unsigned)u.z) & 0xFFFF0000u);
  g1.z = asf(((unsigned)u.w) << 16); g1.w = asf(((unsigned)u.w) & 0xFFFF0000u);
  a0 += g0 * w;
  a1 += g1 * w;
}

// ---------------------------------------------------------------------------
// prep: blocks [0,384): Wcat row blk (bf16) + bcat[blk].
//   row < 128: W_val row (value outputs, head-major o=h*32+d).
//   row in [128,384): h = (row-128)>>6, k = (row-128)&63:
//     k<40 -> W_off[h*40+k]; 40<=k<60 -> W_attn[h*20+k-40]; else zero pad.
//   => proj1 outputs o>=128 form a token-major oa[r][256] record:
//      per head 64 slots = {40 off bf16, 20 attn bf16, 4 pad}.
// blocks [384,512): fold Wc = W2@W1 row -> Wc_bf, bc (for proj2).
// ---------------------------------------------------------------------------
__global__ __launch_bounds__(128) void prep_kernel(
    const float* __restrict__ W_val, const float* __restrict__ b_val,
    const float* __restrict__ W_off, const float* __restrict__ b_off,
    const float* __restrict__ W_attn, const float* __restrict__ b_attn,
    const float* __restrict__ W1, const float* __restrict__ b1,
    const float* __restrict__ W2, const float* __restrict__ b2,
    __hip_bfloat16* __restrict__ Wcat, float* __restrict__ bcat,
    __hip_bfloat16* __restrict__ Wc_bf, float* __restrict__ bc) {
  __shared__ float w2row[128];
  __shared__ float red[128];
  const int blk = blockIdx.x, c = threadIdx.x;
  if (blk < OPAD) {
    float v = 0.f, bv = 0.f;
    if (blk < 128) {
      v = W_val[blk * 128 + c]; bv = b_val[blk];
    } else {
      int h = (blk - 128) >> 6, k = (blk - 128) & 63;
      if (k < 40) { v = W_off[(h * 40 + k) * 128 + c]; bv = b_off[h * 40 + k]; }
      else if (k < 60) { v = W_attn[(h * 20 + k - 40) * 128 + c]; bv = b_attn[h * 20 + k - 40]; }
    }
    Wcat[(size_t)blk * 128 + c] = __float2bfloat16(v);
    if (c == 0) bcat[blk] = bv;
  } else {
    const int o = blk - OPAD;  // 0..127
    w2row[c] = W2[o * 128 + c];
    __syncthreads();
    float acc = 0.f;
    for (int k = 0; k < 128; ++k) acc += w2row[k] * W1[k * 128 + c];
    Wc_bf[(size_t)o * 128 + c] = __float2bfloat16(acc);
    red[c] = w2row[c] * b1[c];
    __syncthreads();
    for (int s = 64; s > 0; s >>= 1) {
      if (c < s) red[c] += red[c + s];
      __syncthreads();
    }
    if (c == 0) bc[o] = b2[o] + red[0];
  }
}

// ---------------------------------------------------------------------------
// proj1: 256 thr, grid (313,2). 64 rows x 192 outs (3 internal 64-out tiles).
// A = (query+query_pos) fp32 -> bf16 staged + fragments hoisted ONCE.
// W tile ti+1 register-prefetched during tile ti's MFMA (latency hidden).
// Epilogue: o<128 -> head-major value (bf16); o>=128 -> token-major
// oa[r*256 + (o-128)] (divide-free, contiguous stores).
// ---------------------------------------------------------------------------
__global__ __launch_bounds__(256) void proj1_kernel(
    const float* __restrict__ query, const float* __restrict__ qpos,
    const __hip_bfloat16* __restrict__ Wcat, const float* __restrict__ bcat,
    __hip_bfloat16* __restrict__ value, __hip_bfloat16* __restrict__ oa) {
  __shared__ __hip_bfloat16 qa[64][128];
  __shared__ __hip_bfloat16 wb[64][128];
  const int t = threadIdx.x;
  const int r0 = blockIdx.x * 64;

  // stage A: fp32 (+qpos) -> bf16, swizzled granules
#pragma unroll
  for (int i = 0; i < 4; ++i) {
    int lin = t + 256 * i;
    int r = lin >> 4, g = lin & 15;
    int c = g << 3;
    float4 v0 = make_float4(0.f, 0.f, 0.f, 0.f);
    float4 v1 = make_float4(0.f, 0.f, 0.f, 0.f);
    if (r0 + r < MROWS) {
      const float* p = query + (size_t)(r0 + r) * CDIM + c;
      v0 = *(const float4*)p;
      v1 = *(const float4*)(p + 4);
      const float* p2 = qpos + (size_t)(r0 + r) * CDIM + c;
      float4 u0 = *(const float4*)p2;
      float4 u1 = *(const float4*)(p2 + 4);
      v0.x += u0.x; v0.y += u0.y; v0.z += u0.z; v0.w += u0.w;
      v1.x += u1.x; v1.y += u1.y; v1.z += u1.z; v1.w += u1.w;
    }
    __hip_bfloat16* dst = &qa[r][(g ^ (r & 7)) << 3];
    dst[0] = __float2bfloat16(v0.x); dst[1] = __float2bfloat16(v0.y);
    dst[2] = __float2bfloat16(v0.z); dst[3] = __float2bfloat16(v0.w);
    dst[4] = __float2bfloat16(v1.x); dst[5] = __float2bfloat16(v1.y);
    dst[6] = __float2bfloat16(v1.z); dst[7] = __float2bfloat16(v1.w);
  }
  // stage W tile 0
  {
    const int ot = blockIdx.y * 192;
#pragma unroll
    for (int i = 0; i < 4; ++i) {
      int lin = t + 256 * i;
      int r = lin >> 4, g = lin & 15;
      short8v w = *(const short8v*)(Wcat + (size_t)(ot + r) * 128 + (g << 3));
      *(short8v*)&wb[r][(g ^ (r & 7)) << 3] = w;
    }
  }
  __syncthreads();

  const int wid = t >> 6;
  const int lane = t & 63;
  const int wr = (wid >> 1) * 32;
  const int wc = (wid & 1) * 32;
  const int lrow = lane & 15;
  const int lk = lane >> 4;

  short8v afr[4][2];
  {
    int ra0 = wr + lrow, ra1 = wr + 16 + lrow;
#pragma unroll
    for (int kk = 0; kk < 4; ++kk) {
      int gb = kk * 4 + lk;
      afr[kk][0] = *(const short8v*)&qa[ra0][(gb ^ (ra0 & 7)) << 3];
      afr[kk][1] = *(const short8v*)&qa[ra1][(gb ^ (ra1 & 7)) << 3];
    }
  }

#pragma unroll
  for (int ti = 0; ti < 3; ++ti) {
    const int ot = blockIdx.y * 192 + ti * 64;

    // register-prefetch next W tile (issue early; consumed after barrier)
    short8v wreg[4];
    if (ti < 2) {
      const int otn = ot + 64;
#pragma unroll
      for (int i = 0; i < 4; ++i) {
        int lin = t + 256 * i;
        int r = lin >> 4, g = lin & 15;
        wreg[i] = *(const short8v*)(Wcat + (size_t)(otn + r) * 128 + (g << 3));
      }
    }

    f32x4 acc[2][2];
#pragma unroll
    for (int mi = 0; mi < 2; ++mi)
#pragma unroll
      for (int ni = 0; ni < 2; ++ni) acc[mi][ni] = (f32x4)(0.f);

#pragma unroll
    for (int kk = 0; kk < 4; ++kk) {
      const int gb = kk * 4 + lk;
      int rb0 = wc + lrow, rb1 = wc + 16 + lrow;
      short8v b0 = *(const short8v*)&wb[rb0][(gb ^ (rb0 & 7)) << 3];
      short8v b1 = *(const short8v*)&wb[rb1][(gb ^ (rb1 & 7)) << 3];
      acc[0][0] = __builtin_amdgcn_mfma_f32_16x16x32_bf16(afr[kk][0], b0, acc[0][0], 0, 0, 0);
      acc[0][1] = __builtin_amdgcn_mfma_f32_16x16x32_bf16(afr[kk][0], b1, acc[0][1], 0, 0, 0);
      acc[1][0] = __builtin_amdgcn_mfma_f32_16x16x32_bf16(afr[kk][1], b0, acc[1][0], 0, 0, 0);
      acc[1][1] = __builtin_amdgcn_mfma_f32_16x16x32_bf16(afr[kk][1], b1, acc[1][1], 0, 0, 0);
    }

    if (ti < 2) {
      __syncthreads();  // all waves done reading wb
#pragma unroll
      for (int i = 0; i < 4; ++i) {
        int lin = t + 256 * i;
        int r = lin >> 4, g = lin & 15;
        *(short8v*)&wb[r][(g ^ (r & 7)) << 3] = wreg[i];
      }
    }

    // epilogue: C/D col = lane&15, row = (lane>>4)*4 + reg
#pragma unroll
    for (int mi = 0; mi < 2; ++mi) {
#pragma unroll
      for (int ni = 0; ni < 2; ++ni) {
#pragma unroll
        for (int reg = 0; reg < 4; ++reg) {
          int r = r0 + wr + mi * 16 + (lane >> 4) * 4 + reg;
          int o = ot + wc + ni * 16 + (lane & 15);
          if (r >= MROWS) continue;
          float v = acc[mi][ni][reg] + bcat[o];
          if (o < 128) {
            int b = r >= NTOK ? 1 : 0;
            int n = r - b * NTOK;
            int h = o >> 5, rem = o & 31;
            value[(((size_t)b * NHEAD + h) * NTOK + n) * 32 + rem] =
                __float2bfloat16(v);
          } else {
            oa[(size_t)r * 256 + (o - 128)] = __float2bfloat16(v);
          }
        }
      }
    }

    if (ti < 2) __syncthreads();
  }
}

// ---------------------------------------------------------------------------
// proj2: 256 thr, grid (313,2). out = A@Wc^T + bc + resid (Wc prefolded).
// A = outat bf16.
// ---------------------------------------------------------------------------
__global__ __launch_bounds__(256) void proj2_kernel(
    const __hip_bfloat16* __restrict__ outat,
    const __hip_bfloat16* __restrict__ Wc_bf, const float* __restrict__ bc,
    const float* __restrict__ resid, float* __restrict__ out) {
  __shared__ __hip_bfloat16 qa[64][128];
  __shared__ __hip_bfloat16 wb[64][128];
  const int t = threadIdx.x;
  const int r0 = blockIdx.x * 64;
  const int ot = blockIdx.y * 64;

#pragma unroll
  for (int i = 0; i < 4; ++i) {
    int lin = t + 256 * i;
    int r = lin >> 4, g = lin & 15;
    short8v v = (short8v)(short)0;
    if (r0 + r < MROWS)
      v = *(const short8v*)(outat + (size_t)(r0 + r) * CDIM + (g << 3));
    *(short8v*)&qa[r][(g ^ (r & 7)) << 3] = v;
  }
#pragma unroll
  for (int i = 0; i < 4; ++i) {
    int lin = t + 256 * i;
    int r = lin >> 4, g = lin & 15;
    short8v w = *(const short8v*)(Wc_bf + (size_t)(ot + r) * 128 + (g << 3));
    *(short8v*)&wb[r][(g ^ (r & 7)) << 3] = w;
  }
  __syncthreads();

  const int wid = t >> 6;
  const int lane = t & 63;
  const int wr = (wid >> 1) * 32;
  const int wc = (wid & 1) * 32;
  const int lrow = lane & 15;
  const int lk = lane >> 4;

  f32x4 acc[2][2];
#pragma unroll
  for (int mi = 0; mi < 2; ++mi)
#pragma unroll
    for (int ni = 0; ni < 2; ++ni) acc[mi][ni] = (f32x4)(0.f);

#pragma unroll
  for (int kk = 0; kk < 4; ++kk) {
    const int gb = kk * 4 + lk;
    int ra0 = wr + lrow, ra1 = wr + 16 + lrow;
    int rb0 = wc + lrow, rb1 = wc + 16 + lrow;
    short8v a0 = *(const short8v*)&qa[ra0][(gb ^ (ra0 & 7)) << 3];
    short8v a1 = *(const short8v*)&qa[ra1][(gb ^ (ra1 & 7)) << 3];
    short8v b0 = *(const short8v*)&wb[rb0][(gb ^ (rb0 & 7)) << 3];
    short8v b1 = *(const short8v*)&wb[rb1][(gb ^ (rb1 & 7)) << 3];
    acc[0][0] = __builtin_amdgcn_mfma_f32_16x16x32_bf16(a0, b0, acc[0][0], 0, 0, 0);
    acc[0][1] = __builtin_amdgcn_mfma_f32_16x16x32_bf16(a0, b1, acc[0][1], 0, 0, 0);
    acc[1][0] = __builtin_amdgcn_mfma_f32_16x16x32_bf16(a1, b0, acc[1][0], 0, 0, 0);
    acc[1][1] = __builtin_amdgcn_mfma_f32_16x16x32_bf16(a1, b1, acc[1][1], 0, 0, 0);
  }

#pragma unroll
  for (int mi = 0; mi < 2; ++mi) {
#pragma unroll
    for (int ni = 0; ni < 2; ++ni) {
#pragma unroll
      for (int reg = 0; reg < 4; ++reg) {
        int r = r0 + wr + mi * 16 + (lane >> 4) * 4 + reg;
        int o = ot + wc + ni * 16 + (lane & 15);
        if (r >= MROWS) continue;
        out[(size_t)r * CDIM + o] =
            acc[mi][ni][reg] + bc[o] + resid[(size_t)r * CDIM + o];
      }
    }
  }
}

// ---------------------------------------------------------------------------
// Sampling (R8 structure): 4 lanes/token, 8 dims/lane; bf16 patch in LDS.
// off+attn now read from the combined token-major oa record (one 128B row):
// per head 64 bf16 = {40 off (packed pairs), 20 attn logits, 4 pad}.
// Four corner accumulator pairs; deferred softmax normalization.
// ---------------------------------------------------------------------------
__global__ __launch_bounds__(256) void sample_kernel(
    const __hip_bfloat16* __restrict__ value,
    const __hip_bfloat16* __restrict__ oa, __hip_bfloat16* __restrict__ outat) {
  const int s = blockIdx.x & 7;
  const int pidx = blockIdx.x >> 3;
  const int PI = pidx % NPATCH, PJ = pidx / NPATCH;
  const int I0 = PI * PTOK, J0 = PJ * PTOK;
  const int b = s >> 2, h = s & 3;

  __shared__ __hip_bfloat16 patch[PDIM * PDIM][CELLPAD];
  const __hip_bfloat16* vglob = value + (size_t)s * NTOK * DHEAD;

  // stage patch: 256 cells x 64B, zeros outside image
#pragma unroll
  for (int it = 0; it < 4; ++it) {
    int lin = threadIdx.x + 256 * it;
    int cell = lin >> 2, part = lin & 3;
    int py = cell >> 4, px = cell & 15;
    int gy = J0 - PHALO + py;
    int gx = I0 - PHALO + px;
    short8v v = (short8v)(short)0;
    if (gy >= 0 && gy < HWDIM && gx >= 0 && gx < HWDIM)
      v = *(const short8v*)(vglob + ((size_t)(gy * HWDIM + gx)) * DHEAD +
                            part * 8);
    *(short8v*)&patch[cell][part * 8] = v;
  }
  __syncthreads();

  const int dl = threadIdx.x & 3;
  const int tok = threadIdx.x >> 2;
  const int li = tok & 7, lj = tok >> 3;
  const int i = I0 + li, j = J0 + lj;
  if (i >= HWDIM || j >= HWDIM) return;
  const int n = i * HWDIM + j;

  // one 128B row: off pairs in u[0..19], attn bf16 pairs in u[20..29]
  union { int4 v4[8]; unsigned u[32]; } d;
  {
    const int4* p4 =
        (const int4*)(oa + ((size_t)(b * NTOK + n)) * 256 + h * 64);
#pragma unroll
    for (int q = 0; q < 8; ++q) d.v4[q] = p4[q];
  }

  float e[NPNT];
  float ssum = 0.f;
#pragma unroll
  for (int q = 0; q < 10; ++q) {
    unsigned uu = d.u[20 + q];
    float e0 = __expf(asf(uu << 16));
    float e1 = __expf(asf(uu & 0xFFFF0000u));
    e[2 * q] = e0; e[2 * q + 1] = e1;
    ssum += e0 + e1;
  }
  const float inv = 1.f / ssum;

  const float fi = (float)i, fj = (float)j;
  f32x4 c0a = (f32x4)(0.f), c0b = (f32x4)(0.f);
  f32x4 c1a = (f32x4)(0.f), c1b = (f32x4)(0.f);
  f32x4 c2a = (f32x4)(0.f), c2b = (f32x4)(0.f);
  f32x4 c3a = (f32x4)(0.f), c3b = (f32x4)(0.f);
#pragma unroll
  for (int p = 0; p < NPNT; ++p) {
    const unsigned up = d.u[p];
    float x = fi + asf(up << 16);
    float y = fj + asf(up & 0xFFFF0000u);
    float aw = e[p];
    float x0f = floorf(x), y0f = floorf(y);
    int ix0 = (int)x0f, iy0 = (int)y0f;
    float wx1 = x - x0f, wy1 = y - y0f;
    float wx0 = 1.f - wx1, wy0 = 1.f - wy1;
    float wya = aw * wy0, wyb = aw * wy1;
    float w00 = wya * wx0, w01 = wya * wx1;
    float w10 = wyb * wx0, w11 = wyb * wx1;
    int ly = iy0 - (J0 - PHALO);
    int lx = ix0 - (I0 - PHALO);
    if ((unsigned)ly <= PDIM - 2 && (unsigned)lx <= PDIM - 2) {
      const __hip_bfloat16* pb = &patch[ly * PDIM + lx][dl * 8];
      acc_cell(pb, w00, c0a, c0b);
      acc_cell(pb + CELLPAD, w01, c1a, c1b);
      acc_cell(pb + PDIM * CELLPAD, w10, c2a, c2b);
      acc_cell(pb + PDIM * CELLPAD + CELLPAD, w11, c3a, c3b);
    } else {
      float wgt[4] = {w00, w01, w10, w11};
#pragma unroll
      for (int cy = 0; cy < 2; ++cy) {
        int iy = iy0 + cy;
        if (iy < 0 || iy >= HWDIM) continue;
#pragma unroll
        for (int cx = 0; cx < 2; ++cx) {
          int ix = ix0 + cx;
          if (ix < 0 || ix >= HWDIM) continue;
          acc_cell(vglob + ((size_t)(iy * HWDIM + ix)) * DHEAD + dl * 8,
                   wgt[cy * 2 + cx], c0a, c0b);
        }
      }
    }
  }
  f32x4 a0 = (c0a + c1a) + (c2a + c3a);
  f32x4 a1 = (c0b + c1b) + (c2b + c3b);

  union { short8v v8; __hip_bfloat16 hh[8]; } o;
#pragma unroll
  for (int k = 0; k < 4; ++k) {
    o.hh[k] = __float2bfloat16(a0[k] * inv);
    o.hh[4 + k] = __float2bfloat16(a1[k] * inv);
  }
  *(short8v*)(outat + ((size_t)b * NTOK + n) * CDIM + h * DHEAD + dl * 8) =
      o.v8;
}

extern "C" void kernel_launch(void* const* d_in, const int* in_sizes, int n_in,
                              void* d_out, int out_size, void* d_ws,
                              size_t ws_size, hipStream_t stream) {
  const float* query = (const float*)d_in[0];
  const float* query_pos = (const float*)d_in[1];
  const float* W_val = (const float*)d_in[2];
  const float* b_val = (const float*)d_in[3];
  const float* W_off = (const float*)d_in[4];
  const float* b_off = (const float*)d_in[5];
  const float* W_attn = (const float*)d_in[6];
  const float* b_attn = (const float*)d_in[7];
  const float* W_out1 = (const float*)d_in[8];
  const float* b_out1 = (const float*)d_in[9];
  const float* W_out2 = (const float*)d_in[10];
  const float* b_out2 = (const float*)d_in[11];
  float* out = (float*)d_out;

  char* ws = (char*)d_ws;
  __hip_bfloat16* value = (__hip_bfloat16*)ws;  // (B*NH,N,32) bf16
  ws += (size_t)MROWS * CDIM * 2;
  __hip_bfloat16* oa = (__hip_bfloat16*)ws;     // (M,256) bf16 off+attn
  ws += (size_t)MROWS * 256 * 2;
  __hip_bfloat16* outat = (__hip_bfloat16*)ws;  // (B,N,C) bf16
  ws += (size_t)MROWS * CDIM * 2;
  float* bcat = (float*)ws; ws += OPAD * 4;
  float* bc = (float*)ws; ws += 128 * 4;
  __hip_bfloat16* Wcat = (__hip_bfloat16*)ws; ws += (size_t)OPAD * 128 * 2;
  __hip_bfloat16* Wc_bf = (__hip_bfloat16*)ws;

  prep_kernel<<<OPAD + 128, 128, 0, stream>>>(
      W_val, b_val, W_off, b_off, W_attn, b_attn, W_out1, b_out1, W_out2,
      b_out2, Wcat, bcat, Wc_bf, bc);

  proj1_kernel<<<dim3(313, 2), 256, 0, stream>>>(query, query_pos, Wcat, bcat,
                                                 value, oa);

  sample_kernel<<<8 * NPATCH * NPATCH, 256, 0, stream>>>(value, oa, outat);

  proj2_kernel<<<dim3(313, 2), 256, 0, stream>>>(outat, Wc_bf, bc, query, out);
}